// Round 7
// baseline (987.504 us; speedup 1.0000x reference)
//
#include <hip/hip_runtime.h>
#include <math.h>

// DNC: B=32,T=64,I=64,O=64,H=512,N=128,W=64,IF=198
// R20 = R19 structure with P1 re-split: 16 jb-slices x 8 bb-groups (4 batches
// per wg). Per-wg unique weight footprint halves (655 -> 327 KB/step), cutting
// the GEMV chain segment ~4.3 -> ~2.1us (per-CU L2 return BW ~60B/cy). One
// float4 weight load feeds 4 batch FMAs. jb = wg>>3 makes same-jb wgs
// XCD-contiguous (chunked dispatch) -> per-XCD weight set ~0.8MB << 4MB L2.
// itf partials now 16-way; P2 phase-1 gathers 8 slots/thread, combined poll.
// P2 phases 2-7 verbatim R19 (proven).
#define Bb 32
#define Tt 64
#define Ii 64
#define Oo 64
#define Hh 512
#define Nn 128
#define Wd 64
#define IFs 198
#define KV 640
#define G4 2048

#define NP1 128          /* 16 jb-slices x 8 bb-groups (4 batches each) */
#define NWG 160          /* + 32 P2 wgs */
#define NT 512

// ---- LDS layout (float offsets). P1/P2 blocks overlap (roles fixed per wg).
// P2 block:
#define P2_MEM    0        /* 128*65 = 8320 */
#define P2_H      8320     /* 576 [h|rvec] */
#define P2_SCR    8896     /* 2048 */
#define P2_ITF    10944    /* 224 */
#define P2_ERASE  11168
#define P2_WVEC   11232
#define P2_USAGE  11296
#define P2_PREC   11424
#define P2_RW     11552
#define P2_WW     11680
#define P2_SCAN   11808
#define P2_SS     11936
#define P2_SCAL   12064    /* 16 */
#define P2_BIF    12080    /* 224 */
#define P2_ALLOC  12304    /* 128 */
// P1 block (W_if rows: 32 cols padded to 36):
#define P1_WIF    0        /* 198*36 = 7128 */
#define P1_BS     7128     /* 128: [gate][l] */
#define P1_V      7256     /* 640 rows x 4 batches = 2560 */
#define P1_CC     9816     /* 128 (4 batches x 32) */
#define P1_HSL    9944     /* 128 */
#define P1_PACC   10072    /* 64*33 float4 = 8448 floats */
#define SMEM_FLOATS 23592  /* 94368 B -> forces 1 wg/CU (full L2 path per wg) */
#define SMEM_BYTES (SMEM_FLOATS * 4)

#define S_WWSUM 0

// WT row permutation: rows = [h(512) | x(64) | rvec(64)].
__device__ __align__(16) float g_WT[KV * G4];
__device__ __align__(16) float g_bsum[G4];
typedef unsigned long long u64;
// Tagged handoffs: u64 = (step_tag << 32) | float_bits. Relaxed agent atomics.
__device__ u64 g_h64[2 * Bb * Hh];    // h, step-parity double buffer, tag t+1
__device__ u64 g_rv64[Bb * Wd];       // rvec(t) tag t+1
__device__ u64 g_if64[Bb * 16 * 200]; // itf partials [b][jb(16)][o pad200] tag t+1

__device__ __forceinline__ float sigf(float v) { return 1.f / (1.f + expf(-v)); }

__device__ __forceinline__ u64 ldrelax(const u64* p) {
  return __hip_atomic_load(p, __ATOMIC_RELAXED, __HIP_MEMORY_SCOPE_AGENT);
}
__device__ __forceinline__ void tstore(u64* p, unsigned tag, float v) {
  u64 val = ((u64)tag << 32) | (u64)__float_as_uint(v);
  __hip_atomic_store(p, val, __ATOMIC_RELAXED, __HIP_MEMORY_SCOPE_AGENT);
}
__device__ __forceinline__ float tval(u64 v) {
  return __uint_as_float((unsigned)(v & 0xffffffffu));
}
// Combined concurrent polls (R19-proven): reload ALL invalid slots per
// iteration so the independent loads overlap in flight.
__device__ __forceinline__ void waitpair(const u64* p0, const u64* p1,
                                         u64& v0, u64& v1, unsigned tag) {
  while (((unsigned)(v0 >> 32)) != tag || ((unsigned)(v1 >> 32)) != tag) {
    __builtin_amdgcn_s_sleep(1);
    v0 = ldrelax(p0);
    v1 = ldrelax(p1);
  }
}
__device__ __forceinline__ void waitquad(const u64* p0, const u64* p1,
                                         const u64* p2, const u64* p3,
                                         u64& v0, u64& v1, u64& v2, u64& v3,
                                         unsigned tag) {
  while (((unsigned)(v0 >> 32)) != tag || ((unsigned)(v1 >> 32)) != tag ||
         ((unsigned)(v2 >> 32)) != tag || ((unsigned)(v3 >> 32)) != tag) {
    __builtin_amdgcn_s_sleep(1);
    v0 = ldrelax(p0);
    v1 = ldrelax(p1);
    v2 = ldrelax(p2);
    v3 = ldrelax(p3);
  }
}

#define TIN 512
__global__ __launch_bounds__(TIN) void dnc_init(const float* __restrict__ W_ih,
                                                const float* __restrict__ W_hh,
                                                const float* __restrict__ b_ih,
                                                const float* __restrict__ b_hh) {
  __shared__ float tile[64][65];
  const int tid = threadIdx.x;
  int i0 = blockIdx.x * blockDim.x + tid;
  int st = gridDim.x * blockDim.x;
  for (int idx = i0; idx < G4; idx += st) g_bsum[idx] = b_ih[idx] + b_hh[idx];
  for (int idx = i0; idx < 2 * Bb * Hh; idx += st) g_h64[idx] = 0ull;
  for (int idx = i0; idx < Bb * Wd; idx += st) g_rv64[idx] = 0ull;
  for (int idx = i0; idx < Bb * 16 * 200; idx += st) g_if64[idx] = 0ull;

  for (int tileId = blockIdx.x; tileId < 320; tileId += gridDim.x) {
    int tc = tileId >> 5, tj = tileId & 31;
    for (int k = tid; k < 64 * 64; k += TIN) {
      int r = k >> 6, cl = k & 63;
      int j = tj * 64 + r, c = tc * 64 + cl;
      tile[r][cl] = (c < 128) ? W_ih[j * 128 + c] : W_hh[j * 512 + (c - 128)];
    }
    __syncthreads();
    for (int k = tid; k < 64 * 64; k += TIN) {
      int cl = k >> 6, rjj = k & 63;
      int c = tc * 64 + cl;
      // rows: h u -> u ; x c -> 512+c ; rvec -> 576+(c-64)  (== 512+c)
      int rp = (c < 128) ? (512 + c) : (c - 128);
      g_WT[(size_t)rp * G4 + tj * 64 + rjj] = tile[rjj][cl];
    }
    __syncthreads();
  }
}

__global__ __launch_bounds__(NT) void dnc_main(const float* __restrict__ x,
                                               const float* __restrict__ W_if,
                                               const float* __restrict__ b_if,
                                               const float* __restrict__ W_out,
                                               const float* __restrict__ b_out,
                                               float* __restrict__ out) {
  extern __shared__ float sm[];
  const int tid = threadIdx.x;
  const int wg = blockIdx.x;

  if (wg < NP1) {
    // ======================= P1: gates GEMV (32 h-units, 4 batches) + LSTM + itf
    const int jb = wg >> 3;   // 0..15, XCD-contiguous
    const int bb = wg & 7;    // 0..7
    const int b0 = bb * 4;
    for (int i = tid; i < IFs * 32; i += NT) {
      int o = i >> 5, c = i & 31;
      sm[P1_WIF + o * 36 + c] = W_if[(size_t)o * Hh + jb * 32 + c];
    }
    if (tid < 128) {
      int g = tid >> 5, l = tid & 31;
      sm[P1_BS + tid] = g_bsum[g * 512 + jb * 32 + l];
      sm[P1_CC + tid] = 0.f;
    }
    __syncthreads();

    for (int t = 0; t < Tt; ++t) {
      {  // stage h(t-1) (4 batches, concurrent quad poll) + x
        const u64* hsrc = g_h64 + (size_t)((t + 1) & 1) * (Bb * Hh);
        const int u = tid;
        const u64* a0 = hsrc + (size_t)(b0 + 0) * Hh + u;
        const u64* a1 = hsrc + (size_t)(b0 + 1) * Hh + u;
        const u64* a2 = hsrc + (size_t)(b0 + 2) * Hh + u;
        const u64* a3 = hsrc + (size_t)(b0 + 3) * Hh + u;
        u64 v0 = ldrelax(a0), v1 = ldrelax(a1), v2 = ldrelax(a2), v3 = ldrelax(a3);
        waitquad(a0, a1, a2, a3, v0, v1, v2, v3, (unsigned)t);
        float4 hh;
        hh.x = tval(v0); hh.y = tval(v1); hh.z = tval(v2); hh.w = tval(v3);
        ((float4*)(sm + P1_V))[u] = hh;
        if (tid < 256) {
          const int bl2 = tid >> 6, i = tid & 63;
          sm[P1_V + (512 + i) * 4 + bl2] = x[((size_t)(b0 + bl2) * Tt + t) * Ii + i];
        }
      }
      __syncthreads();

      {  // GEMV: 640 rows x 32 float4-cols; one weight load -> 4 batch FMAs
        const int fg = tid & 31, ks = tid >> 5;  // ks 0..15, rows ks*40..+39
        const int fcol = ((fg >> 3) * 128) + jb * 8 + (fg & 7);
        const float4* vp = (const float4*)(sm + P1_V) + ks * 40;
        const float4* wp = (const float4*)g_WT + (size_t)(ks * 40) * 512 + fcol;
        if (ks >= 14) {  // wave 7 owns rvec rows 576..639: concurrent quad wait
          const int j = tid & 63;
          const u64* r0 = g_rv64 + (size_t)(b0 + 0) * Wd + j;
          const u64* r1 = g_rv64 + (size_t)(b0 + 1) * Wd + j;
          const u64* r2 = g_rv64 + (size_t)(b0 + 2) * Wd + j;
          const u64* r3 = g_rv64 + (size_t)(b0 + 3) * Wd + j;
          u64 u0 = ldrelax(r0), u1 = ldrelax(r1), u2 = ldrelax(r2), u3 = ldrelax(r3);
          waitquad(r0, r1, r2, r3, u0, u1, u2, u3, (unsigned)t);
          float4 rv;
          rv.x = tval(u0); rv.y = tval(u1); rv.z = tval(u2); rv.w = tval(u3);
          ((float4*)(sm + P1_V))[576 + j] = rv;  // same-wave write->read
        }
        float4 a0 = {0.f, 0.f, 0.f, 0.f}, a1 = {0.f, 0.f, 0.f, 0.f};
        float4 a2 = {0.f, 0.f, 0.f, 0.f}, a3 = {0.f, 0.f, 0.f, 0.f};
#pragma unroll 4
        for (int r = 0; r < 40; ++r) {
          float4 w4 = wp[(size_t)r * 512];
          float4 vv = vp[r];
          a0.x += w4.x * vv.x; a0.y += w4.y * vv.x; a0.z += w4.z * vv.x; a0.w += w4.w * vv.x;
          a1.x += w4.x * vv.y; a1.y += w4.y * vv.y; a1.z += w4.z * vv.y; a1.w += w4.w * vv.y;
          a2.x += w4.x * vv.z; a2.y += w4.y * vv.z; a2.z += w4.z * vv.z; a2.w += w4.w * vv.z;
          a3.x += w4.x * vv.w; a3.y += w4.y * vv.w; a3.z += w4.z * vv.w; a3.w += w4.w * vv.w;
        }
        float4* pacc = (float4*)(sm + P1_PACC);
        pacc[(ks * 4 + 0) * 33 + fg] = a0;
        pacc[(ks * 4 + 1) * 33 + fg] = a1;
        pacc[(ks * 4 + 2) * 33 + fg] = a2;
        pacc[(ks * 4 + 3) * 33 + fg] = a3;
      }
      __syncthreads();
      if (tid < 128) {  // K-reduce (16 partials) + LSTM; h published tagged
        const int bl = tid >> 5, l = tid & 31;
        const float* pb = sm + P1_PACC + bl * 132 + l;
        float gv0 = 0.f, gv1 = 0.f, gv2 = 0.f, gv3 = 0.f;
#pragma unroll
        for (int ks = 0; ks < 16; ++ks) {
          const float* pk = pb + ks * 528;
          gv0 += pk[0];
          gv1 += pk[32];
          gv2 += pk[64];
          gv3 += pk[96];
        }
        float ig = gv0 + sm[P1_BS + l];
        float fg = gv1 + sm[P1_BS + 32 + l];
        float gg = gv2 + sm[P1_BS + 64 + l];
        float og = gv3 + sm[P1_BS + 96 + l];
        float co = sm[P1_CC + tid];
        float cn = sigf(fg) * co + sigf(ig) * tanhf(gg);
        float hn = sigf(og) * tanhf(cn);
        sm[P1_CC + tid] = cn;
        sm[P1_HSL + tid] = hn;
        tstore(g_h64 + (size_t)(t & 1) * (Bb * Hh) + (size_t)(b0 + bl) * Hh + jb * 32 + l,
               (unsigned)(t + 1), hn);
      }
      __syncthreads();
      if (tid < 2 * IFs) {  // itf partials (32-col dot), 2 batches per thread
        const int o = tid >> 1, blh = tid & 1;
        const float4* wr = (const float4*)(sm + P1_WIF + o * 36);
        const float4* hA = (const float4*)(sm + P1_HSL) + (blh * 2 + 0) * 8;
        const float4* hB = (const float4*)(sm + P1_HSL) + (blh * 2 + 1) * 8;
        float accA = 0.f, accB = 0.f;
#pragma unroll
        for (int c4 = 0; c4 < 8; ++c4) {
          float4 w = wr[c4];
          float4 ha = hA[c4];
          float4 hb = hB[c4];
          accA += w.x * ha.x + w.y * ha.y + w.z * ha.z + w.w * ha.w;
          accB += w.x * hb.x + w.y * hb.y + w.z * hb.z + w.w * hb.w;
        }
        tstore(g_if64 + ((size_t)(b0 + blh * 2 + 0) * 16 + jb) * 200 + o,
               (unsigned)(t + 1), accA);
        tstore(g_if64 + ((size_t)(b0 + blh * 2 + 1) * 16 + jb) * 200 + o,
               (unsigned)(t + 1), accB);
      }
    }
  } else {
    // ======================= P2: DNC memory for batch b — R19 verbatim except
    // phase-1 gathers 16 jb partials (8 per thread, one combined poll).
    const int b = wg - NP1;
    float* SCR = sm + P2_SCR;
    float regL[32], regLT[32];
#pragma unroll
    for (int k = 0; k < 32; ++k) { regL[k] = 0.f; regLT[k] = 0.f; }
    for (int i = tid; i < Nn * 65; i += NT) sm[P2_MEM + i] = 0.f;
    if (tid < 128) { sm[P2_USAGE + tid] = 0.f; sm[P2_PREC + tid] = 0.f; sm[P2_RW + tid] = 0.f; }
    if (tid < IFs) sm[P2_BIF + tid] = b_if[tid];
    __syncthreads();
    // prologue: alloc for t=0 from usage=0
    if (tid < 64) {
      const int li = tid, i0 = 2 * li, i1 = i0 + 1;
      float u0 = sm[P2_USAGE + i0], u1 = sm[P2_USAGE + i1];
      int r0 = 0, r1 = 0;
      for (int jc = 0; jc < 32; ++jc) {
        float4 uj4 = *(const float4*)(sm + P2_USAGE + jc * 4);
#pragma unroll
        for (int e = 0; e < 4; ++e) {
          float uj = (&uj4.x)[e];
          int j = jc * 4 + e;
          r0 += (uj < u0 || (uj == u0 && j < i0)) ? 1 : 0;
          r1 += (uj < u1 || (uj == u1 && j < i1)) ? 1 : 0;
        }
      }
      sm[P2_SS + r0] = u0;
      sm[P2_SS + r1] = u1;
      float s0 = sm[P2_SS + i0], s1 = sm[P2_SS + i1];
      float p = s0 * s1;
#pragma unroll
      for (int off = 1; off < 64; off <<= 1) {
        float v = __shfl_up(p, off, 64);
        if (li >= off) p *= v;
      }
      float E = __shfl_up(p, 1, 64);
      if (li == 0) E = 1.f;
      sm[P2_SCAN + i0] = E * s0;
      sm[P2_SCAN + i1] = E * s0 * s1;
      float ex0 = (r0 > 0) ? sm[P2_SCAN + r0 - 1] : 1.f;
      float ex1 = (r1 > 0) ? sm[P2_SCAN + r1 - 1] : 1.f;
      sm[P2_ALLOC + i0] = (1.f - u0) * ex0;
      sm[P2_ALLOC + i1] = (1.f - u1) * ex1;
    }
    __syncthreads();

    for (int t = 0; t < Tt; ++t) {
      // ---- phase 1: tagged itf gather — 8 slots/thread, combined poll
      if (tid < 2 * IFs) {
        const int o = tid >> 1, hf = tid & 1;
        const u64* base = g_if64 + ((size_t)b * 16 + hf * 8) * 200 + o;
        const u64 *q0 = base, *q1 = base + 200, *q2 = base + 400, *q3 = base + 600;
        const u64 *q4 = base + 800, *q5 = base + 1000, *q6 = base + 1200, *q7 = base + 1400;
        u64 w0 = ldrelax(q0), w1 = ldrelax(q1), w2 = ldrelax(q2), w3 = ldrelax(q3);
        u64 w4 = ldrelax(q4), w5 = ldrelax(q5), w6 = ldrelax(q6), w7 = ldrelax(q7);
        const unsigned tg = (unsigned)(t + 1);
        while (((unsigned)(w0 >> 32)) != tg || ((unsigned)(w1 >> 32)) != tg ||
               ((unsigned)(w2 >> 32)) != tg || ((unsigned)(w3 >> 32)) != tg ||
               ((unsigned)(w4 >> 32)) != tg || ((unsigned)(w5 >> 32)) != tg ||
               ((unsigned)(w6 >> 32)) != tg || ((unsigned)(w7 >> 32)) != tg) {
          __builtin_amdgcn_s_sleep(1);
          w0 = ldrelax(q0); w1 = ldrelax(q1); w2 = ldrelax(q2); w3 = ldrelax(q3);
          w4 = ldrelax(q4); w5 = ldrelax(q5); w6 = ldrelax(q6); w7 = ldrelax(q7);
        }
        float s = tval(w0) + tval(w1) + tval(w2) + tval(w3)
                + tval(w4) + tval(w5) + tval(w6) + tval(w7);
        s += __shfl_xor(s, 1, 64);
        if (hf == 0) sm[P2_ITF + o] = s + sm[P2_BIF + o];
      }
      __syncthreads();
      // ---- phase 2: wave0 short block (scalars + ww from ALLOC + usage + wwsum)
      float kn_r = 0.f, rstr_r = 0.f, rm0_r = 0.f, rm1_r = 0.f, rm2_r = 0.f;
      if (tid < 64) {
        const int li = tid, i0 = 2 * li, i1 = i0 + 1;
        float wgag = sigf(sm[P2_ITF + 128]) * sigf(sm[P2_ITF + 129]);
        float rs = sm[P2_ITF + 194];
        rstr_r = (rs > 20.f) ? rs : log1pf(expf(rs));
        float m0 = sm[P2_ITF + 195], m1 = sm[P2_ITF + 196], m2 = sm[P2_ITF + 197];
        float mx = fmaxf(m0, fmaxf(m1, m2));
        float e0 = expf(m0 - mx), e1 = expf(m1 - mx), e2 = expf(m2 - mx);
        float es = e0 + e1 + e2;
        rm0_r = e0 / es; rm1_r = e1 / es; rm2_r = e2 / es;
        float rk = sm[P2_ITF + li];
        sm[P2_ERASE + li] = sigf(rk);
        sm[P2_WVEC + li] = sm[P2_ITF + 64 + li];
        float sq = rk * rk;
#pragma unroll
        for (int off = 32; off > 0; off >>= 1) sq += __shfl_xor(sq, off, 64);
        kn_r = sqrtf(sq) + 1e-8f;
        float u0 = sm[P2_USAGE + i0], u1 = sm[P2_USAGE + i1];
        float w0 = wgag * sm[P2_ALLOC + i0];
        float w1 = wgag * sm[P2_ALLOC + i1];
        sm[P2_WW + i0] = w0; sm[P2_WW + i1] = w1;
        sm[P2_USAGE + i0] = u0 + (1.f - u0) * w0;
        sm[P2_USAGE + i1] = u1 + (1.f - u1) * w1;
        float wws = w0 + w1;
#pragma unroll
        for (int off = 32; off > 0; off >>= 1) wws += __shfl_xor(wws, off, 64);
        if (li == 0) sm[P2_SCAL + S_WWSUM] = wws;
      }
      __syncthreads();
      // ---- phase 3: pass1 (fused mem+dot+mn + register link + bw/fw partials)
      {
        const int n = tid & 127, ws = tid >> 7;
        float4 er[4], wv[4], kf[4];
#pragma unroll
        for (int r = 0; r < 4; ++r) {
          er[r] = *(const float4*)(sm + P2_ERASE + ws * 16 + r * 4);
          wv[r] = *(const float4*)(sm + P2_WVEC + ws * 16 + r * 4);
          kf[r] = *(const float4*)(sm + P2_ITF + ws * 16 + r * 4);
        }
        float wwn = sm[P2_WW + n];
        float dotp = 0.f, mnp = 0.f;
        const int base = P2_MEM + n * 65 + ws * 16;
#pragma unroll
        for (int q = 0; q < 16; ++q) {
          float m = sm[base + q];
          float ee = (&er[q >> 2].x)[q & 3];
          float vv = (&wv[q >> 2].x)[q & 3];
          float kk = (&kf[q >> 2].x)[q & 3];
          m = m * (1.f - wwn * ee) + wwn * vv;
          sm[base + q] = m;
          dotp += kk * m;
          mnp += m * m;
        }
        SCR[ws * 128 + n] = dotp;
        SCR[512 + ws * 128 + n] = mnp;
        const int m = n, ns = ws;
        float wwm = wwn;
        float prn = sm[P2_PREC + m];
        float bwp = 0.f, fwp = 0.f;
#pragma unroll
        for (int kq = 0; kq < 8; ++kq) {
          float4 ww4 = *(const float4*)(sm + P2_WW + ns * 32 + kq * 4);
          float4 pr4 = *(const float4*)(sm + P2_PREC + ns * 32 + kq * 4);
          float4 rw4 = *(const float4*)(sm + P2_RW + ns * 32 + kq * 4);
#pragma unroll
          for (int e = 0; e < 4; ++e) {
            int k = kq * 4 + e;
            int nn = ns * 32 + k;
            float wwo = (&ww4.x)[e];
            float pro = (&pr4.x)[e];
            float rwo = (&rw4.x)[e];
            float L = regL[k];
            L = (1.f - wwo - wwm) * L + pro * wwm;
            if (nn == m) L = 0.f;
            regL[k] = L;
            bwp += L * rwo;
            float LT = regLT[k];
            LT = (1.f - wwm - wwo) * LT + prn * wwo;
            if (nn == m) LT = 0.f;
            regLT[k] = LT;
            fwp += LT * rwo;
          }
        }
        SCR[1024 + ns * 128 + m] = bwp;
        SCR[1536 + ns * 128 + m] = fwp;
      }
      __syncthreads();
      // ---- phase 4: softmax + combine + normalize (pass2 FUSED: read partials)
      if (tid < 64) {
        int i0 = 2 * tid, i1 = i0 + 1;
        float d0 = SCR[i0] + SCR[128 + i0] + SCR[256 + i0] + SCR[384 + i0];
        float d1 = SCR[i1] + SCR[128 + i1] + SCR[256 + i1] + SCR[384 + i1];
        float mn0 = sqrtf(SCR[512 + i0] + SCR[640 + i0] + SCR[768 + i0] + SCR[896 + i0]) + 1e-8f;
        float mn1 = sqrtf(SCR[512 + i1] + SCR[640 + i1] + SCR[768 + i1] + SCR[896 + i1]) + 1e-8f;
        float bw0 = SCR[1024 + i0] + SCR[1152 + i0] + SCR[1280 + i0] + SCR[1408 + i0];
        float bw1 = SCR[1024 + i1] + SCR[1152 + i1] + SCR[1280 + i1] + SCR[1408 + i1];
        float fw0 = SCR[1536 + i0] + SCR[1664 + i0] + SCR[1792 + i0] + SCR[1920 + i0];
        float fw1 = SCR[1536 + i1] + SCR[1664 + i1] + SCR[1792 + i1] + SCR[1920 + i1];
        float q0 = d0 / (kn_r * mn0) * rstr_r;
        float q1 = d1 / (kn_r * mn1) * rstr_r;
        float mx = fmaxf(q0, q1);
#pragma unroll
        for (int off = 32; off > 0; off >>= 1) mx = fmaxf(mx, __shfl_xor(mx, off, 64));
        float e0 = expf(q0 - mx), e1 = expf(q1 - mx);
        float es = e0 + e1;
#pragma unroll
        for (int off = 32; off > 0; off >>= 1) es += __shfl_xor(es, off, 64);
        float wv0 = rm0_r * bw0 + rm1_r * fw0 + rm2_r * (e0 / es) + 1e-8f;
        float wv1 = rm0_r * bw1 + rm1_r * fw1 + rm2_r * (e1 / es) + 1e-8f;
        float wsum = wv0 + wv1;
#pragma unroll
        for (int off = 32; off > 0; off >>= 1) wsum += __shfl_xor(wsum, off, 64);
        sm[P2_RW + i0] = wv0 / wsum;
        sm[P2_RW + i1] = wv1 / wsum;
      }
      __syncthreads();
      // ---- phase 5: rvec partials
      {
        const int w = tid & 63, ns8 = tid >> 6;
        float4 rw4[4];
#pragma unroll
        for (int r = 0; r < 4; ++r)
          rw4[r] = *(const float4*)(sm + P2_RW + ns8 * 16 + r * 4);
        float p = 0.f;
#pragma unroll
        for (int k = 0; k < 16; ++k)
          p += (&rw4[k >> 2].x)[k & 3] * sm[P2_MEM + (ns8 * 16 + k) * 65 + w];
        SCR[ns8 * 64 + w] = p;
      }
      __syncthreads();
      // ---- phase 6 (merged): rvec reduce+publish | h gather | alloc | prec
      if (tid < 64) {          // rvec reduce -> tagged store (critical-path exit)
        float r = 0.f;
#pragma unroll
        for (int s2 = 0; s2 < 8; ++s2) r += SCR[s2 * 64 + tid];
        sm[P2_H + 512 + tid] = r;
        tstore(g_rv64 + (size_t)b * Wd + tid, (unsigned)(t + 1), r);
      } else if (tid < 320) {  // tagged h gather — concurrent wait
        const int idx = tid - 64;
        const u64* hsrc = g_h64 + (size_t)(t & 1) * (Bb * Hh) + (size_t)b * Hh;
        const u64* a0 = hsrc + idx * 2;
        const u64* a1 = hsrc + idx * 2 + 1;
        u64 v0 = ldrelax(a0), v1 = ldrelax(a1);
        waitpair(a0, a1, v0, v1, (unsigned)(t + 1));
        sm[P2_H + idx * 2] = tval(v0);
        sm[P2_H + idx * 2 + 1] = tval(v1);
      } else if (tid < 384) {  // next step's alloc from usage(t) (wave 5)
        const int li = tid - 320, i0 = 2 * li, i1 = i0 + 1;
        float u0 = sm[P2_USAGE + i0], u1 = sm[P2_USAGE + i1];
        int r0 = 0, r1 = 0;
        for (int jc = 0; jc < 32; ++jc) {
          float4 uj4 = *(const float4*)(sm + P2_USAGE + jc * 4);
#pragma unroll
          for (int e = 0; e < 4; ++e) {
            float uj = (&uj4.x)[e];
            int j = jc * 4 + e;
            r0 += (uj < u0 || (uj == u0 && j < i0)) ? 1 : 0;
            r1 += (uj < u1 || (uj == u1 && j < i1)) ? 1 : 0;
          }
        }
        sm[P2_SS + r0] = u0;
        sm[P2_SS + r1] = u1;
        float s0 = sm[P2_SS + i0], s1 = sm[P2_SS + i1];
        float p = s0 * s1;
#pragma unroll
        for (int off = 1; off < 64; off <<= 1) {
          float v = __shfl_up(p, off, 64);
          if (li >= off) p *= v;
        }
        float E = __shfl_up(p, 1, 64);
        if (li == 0) E = 1.f;
        sm[P2_SCAN + i0] = E * s0;
        sm[P2_SCAN + i1] = E * s0 * s1;
        float ex0 = (r0 > 0) ? sm[P2_SCAN + r0 - 1] : 1.f;
        float ex1 = (r1 > 0) ? sm[P2_SCAN + r1 - 1] : 1.f;
        sm[P2_ALLOC + i0] = (1.f - u0) * ex0;
        sm[P2_ALLOC + i1] = (1.f - u1) * ex1;
      } else {                 // prec update (hoisted from old pass2)
        const int n = tid - 384;   // 0..127
        float wws = sm[P2_SCAL + S_WWSUM];
        sm[P2_PREC + n] = (1.f - wws) * sm[P2_PREC + n] + sm[P2_WW + n];
      }
      __syncthreads();
      // ---- phase 7: out projection (no trailing barrier needed)
      {
        const int o = tid >> 3, seg = tid & 7;
        const float4* wrow = (const float4*)(W_out + (size_t)o * 576) + seg * 18;
        const float4* hb = (const float4*)(sm + P2_H) + seg * 18;
        float p = 0.f;
#pragma unroll
        for (int q = 0; q < 18; ++q) {
          float4 w = wrow[q]; float4 h = hb[q];
          p += w.x * h.x + w.y * h.y + w.z * h.z + w.w * h.w;
        }
        p += __shfl_down(p, 4, 8);
        p += __shfl_down(p, 2, 8);
        p += __shfl_down(p, 1, 8);
        if (seg == 0) out[((size_t)b * Tt + t) * Oo + o] = p + b_out[o];
      }
    }
  }
}

extern "C" void kernel_launch(void* const* d_in, const int* in_sizes, int n_in,
                              void* d_out, int out_size, void* d_ws, size_t ws_size,
                              hipStream_t stream) {
  (void)in_sizes; (void)n_in; (void)d_ws; (void)ws_size; (void)out_size;
  const float* x    = (const float*)d_in[0];
  const float* W_ih = (const float*)d_in[1];
  const float* W_hh = (const float*)d_in[2];
  const float* b_ih = (const float*)d_in[3];
  const float* b_hh = (const float*)d_in[4];
  const float* W_if = (const float*)d_in[5];
  const float* b_if = (const float*)d_in[6];
  const float* W_out = (const float*)d_in[7];
  const float* b_out = (const float*)d_in[8];
  float* out = (float*)d_out;

  dnc_init<<<320, TIN, 0, stream>>>(W_ih, W_hh, b_ih, b_hh);

  hipFuncSetAttribute((const void*)dnc_main,
                      hipFuncAttributeMaxDynamicSharedMemorySize, SMEM_BYTES);

  void* args[] = {(void*)&x, (void*)&W_if, (void*)&b_if,
                  (void*)&W_out, (void*)&b_out, (void*)&out};
  hipLaunchCooperativeKernel((void*)dnc_main, dim3(NWG), dim3(NT), args,
                             SMEM_BYTES, stream);
}

// Round 8
// 900.539 us; speedup vs baseline: 1.0966x; 1.0966x over previous
//
#include <hip/hip_runtime.h>
#include <math.h>

// DNC: B=32,T=64,I=64,O=64,H=512,N=128,W=64,IF=198
// R21 = R20 with the XCD mapping FIXED: dispatch is ROUND-ROBIN (XCD = wg%8),
// so jb must live in the low bits. jb = wg&15, bb = wg>>4 -> same-jb wgs all
// land on XCD jb%8; each XCD hosts 2 slices x 327KB = 654KB (L2-resident).
// R20's jb=wg>>3 put all 16 slices on every XCD -> 5.24MB L2 thrash
// (FETCH 59MB -> 1.34GB). This cleanly tests the footprint-halving theory.
#define Bb 32
#define Tt 64
#define Ii 64
#define Oo 64
#define Hh 512
#define Nn 128
#define Wd 64
#define IFs 198
#define KV 640
#define G4 2048

#define NP1 128          /* 16 jb-slices x 8 bb-groups (4 batches each) */
#define NWG 160          /* + 32 P2 wgs */
#define NT 512

// ---- LDS layout (float offsets). P1/P2 blocks overlap (roles fixed per wg).
// P2 block:
#define P2_MEM    0        /* 128*65 = 8320 */
#define P2_H      8320     /* 576 [h|rvec] */
#define P2_SCR    8896     /* 2048 */
#define P2_ITF    10944    /* 224 */
#define P2_ERASE  11168
#define P2_WVEC   11232
#define P2_USAGE  11296
#define P2_PREC   11424
#define P2_RW     11552
#define P2_WW     11680
#define P2_SCAN   11808
#define P2_SS     11936
#define P2_SCAL   12064    /* 16 */
#define P2_BIF    12080    /* 224 */
#define P2_ALLOC  12304    /* 128 */
// P1 block (W_if rows: 32 cols padded to 36):
#define P1_WIF    0        /* 198*36 = 7128 */
#define P1_BS     7128     /* 128: [gate][l] */
#define P1_V      7256     /* 640 rows x 4 batches = 2560 */
#define P1_CC     9816     /* 128 (4 batches x 32) */
#define P1_HSL    9944     /* 128 */
#define P1_PACC   10072    /* 64*33 float4 = 8448 floats */
#define SMEM_FLOATS 23592  /* 94368 B -> 1 wg/CU */
#define SMEM_BYTES (SMEM_FLOATS * 4)

#define S_WWSUM 0

// WT row permutation: rows = [h(512) | x(64) | rvec(64)].
__device__ __align__(16) float g_WT[KV * G4];
__device__ __align__(16) float g_bsum[G4];
typedef unsigned long long u64;
// Tagged handoffs: u64 = (step_tag << 32) | float_bits. Relaxed agent atomics.
__device__ u64 g_h64[2 * Bb * Hh];    // h, step-parity double buffer, tag t+1
__device__ u64 g_rv64[Bb * Wd];       // rvec(t) tag t+1
__device__ u64 g_if64[Bb * 16 * 200]; // itf partials [b][jb(16)][o pad200] tag t+1

__device__ __forceinline__ float sigf(float v) { return 1.f / (1.f + expf(-v)); }

__device__ __forceinline__ u64 ldrelax(const u64* p) {
  return __hip_atomic_load(p, __ATOMIC_RELAXED, __HIP_MEMORY_SCOPE_AGENT);
}
__device__ __forceinline__ void tstore(u64* p, unsigned tag, float v) {
  u64 val = ((u64)tag << 32) | (u64)__float_as_uint(v);
  __hip_atomic_store(p, val, __ATOMIC_RELAXED, __HIP_MEMORY_SCOPE_AGENT);
}
__device__ __forceinline__ float tval(u64 v) {
  return __uint_as_float((unsigned)(v & 0xffffffffu));
}
// Combined concurrent polls (R19-proven): reload ALL invalid slots per
// iteration so the independent loads overlap in flight.
__device__ __forceinline__ void waitpair(const u64* p0, const u64* p1,
                                         u64& v0, u64& v1, unsigned tag) {
  while (((unsigned)(v0 >> 32)) != tag || ((unsigned)(v1 >> 32)) != tag) {
    __builtin_amdgcn_s_sleep(1);
    v0 = ldrelax(p0);
    v1 = ldrelax(p1);
  }
}
__device__ __forceinline__ void waitquad(const u64* p0, const u64* p1,
                                         const u64* p2, const u64* p3,
                                         u64& v0, u64& v1, u64& v2, u64& v3,
                                         unsigned tag) {
  while (((unsigned)(v0 >> 32)) != tag || ((unsigned)(v1 >> 32)) != tag ||
         ((unsigned)(v2 >> 32)) != tag || ((unsigned)(v3 >> 32)) != tag) {
    __builtin_amdgcn_s_sleep(1);
    v0 = ldrelax(p0);
    v1 = ldrelax(p1);
    v2 = ldrelax(p2);
    v3 = ldrelax(p3);
  }
}

#define TIN 512
__global__ __launch_bounds__(TIN) void dnc_init(const float* __restrict__ W_ih,
                                                const float* __restrict__ W_hh,
                                                const float* __restrict__ b_ih,
                                                const float* __restrict__ b_hh) {
  __shared__ float tile[64][65];
  const int tid = threadIdx.x;
  int i0 = blockIdx.x * blockDim.x + tid;
  int st = gridDim.x * blockDim.x;
  for (int idx = i0; idx < G4; idx += st) g_bsum[idx] = b_ih[idx] + b_hh[idx];
  for (int idx = i0; idx < 2 * Bb * Hh; idx += st) g_h64[idx] = 0ull;
  for (int idx = i0; idx < Bb * Wd; idx += st) g_rv64[idx] = 0ull;
  for (int idx = i0; idx < Bb * 16 * 200; idx += st) g_if64[idx] = 0ull;

  for (int tileId = blockIdx.x; tileId < 320; tileId += gridDim.x) {
    int tc = tileId >> 5, tj = tileId & 31;
    for (int k = tid; k < 64 * 64; k += TIN) {
      int r = k >> 6, cl = k & 63;
      int j = tj * 64 + r, c = tc * 64 + cl;
      tile[r][cl] = (c < 128) ? W_ih[j * 128 + c] : W_hh[j * 512 + (c - 128)];
    }
    __syncthreads();
    for (int k = tid; k < 64 * 64; k += TIN) {
      int cl = k >> 6, rjj = k & 63;
      int c = tc * 64 + cl;
      // rows: h u -> u ; x c -> 512+c ; rvec -> 576+(c-64)  (== 512+c)
      int rp = (c < 128) ? (512 + c) : (c - 128);
      g_WT[(size_t)rp * G4 + tj * 64 + rjj] = tile[rjj][cl];
    }
    __syncthreads();
  }
}

__global__ __launch_bounds__(NT) void dnc_main(const float* __restrict__ x,
                                               const float* __restrict__ W_if,
                                               const float* __restrict__ b_if,
                                               const float* __restrict__ W_out,
                                               const float* __restrict__ b_out,
                                               float* __restrict__ out) {
  extern __shared__ float sm[];
  const int tid = threadIdx.x;
  const int wg = blockIdx.x;

  if (wg < NP1) {
    // ======================= P1: gates GEMV (32 h-units, 4 batches) + LSTM + itf
    const int jb = wg & 15;   // low bits -> same-jb wgs share an XCD (rr dispatch)
    const int bb = wg >> 4;   // 0..7
    const int b0 = bb * 4;
    for (int i = tid; i < IFs * 32; i += NT) {
      int o = i >> 5, c = i & 31;
      sm[P1_WIF + o * 36 + c] = W_if[(size_t)o * Hh + jb * 32 + c];
    }
    if (tid < 128) {
      int g = tid >> 5, l = tid & 31;
      sm[P1_BS + tid] = g_bsum[g * 512 + jb * 32 + l];
      sm[P1_CC + tid] = 0.f;
    }
    __syncthreads();

    for (int t = 0; t < Tt; ++t) {
      {  // stage h(t-1) (4 batches, concurrent quad poll) + x
        const u64* hsrc = g_h64 + (size_t)((t + 1) & 1) * (Bb * Hh);
        const int u = tid;
        const u64* a0 = hsrc + (size_t)(b0 + 0) * Hh + u;
        const u64* a1 = hsrc + (size_t)(b0 + 1) * Hh + u;
        const u64* a2 = hsrc + (size_t)(b0 + 2) * Hh + u;
        const u64* a3 = hsrc + (size_t)(b0 + 3) * Hh + u;
        u64 v0 = ldrelax(a0), v1 = ldrelax(a1), v2 = ldrelax(a2), v3 = ldrelax(a3);
        waitquad(a0, a1, a2, a3, v0, v1, v2, v3, (unsigned)t);
        float4 hh;
        hh.x = tval(v0); hh.y = tval(v1); hh.z = tval(v2); hh.w = tval(v3);
        ((float4*)(sm + P1_V))[u] = hh;
        if (tid < 256) {
          const int bl2 = tid >> 6, i = tid & 63;
          sm[P1_V + (512 + i) * 4 + bl2] = x[((size_t)(b0 + bl2) * Tt + t) * Ii + i];
        }
      }
      __syncthreads();

      {  // GEMV: 640 rows x 32 float4-cols; one weight load -> 4 batch FMAs
        const int fg = tid & 31, ks = tid >> 5;  // ks 0..15, rows ks*40..+39
        const int fcol = ((fg >> 3) * 128) + jb * 8 + (fg & 7);
        const float4* vp = (const float4*)(sm + P1_V) + ks * 40;
        const float4* wp = (const float4*)g_WT + (size_t)(ks * 40) * 512 + fcol;
        if (ks >= 14) {  // wave 7 owns rvec rows 576..639: concurrent quad wait
          const int j = tid & 63;
          const u64* r0 = g_rv64 + (size_t)(b0 + 0) * Wd + j;
          const u64* r1 = g_rv64 + (size_t)(b0 + 1) * Wd + j;
          const u64* r2 = g_rv64 + (size_t)(b0 + 2) * Wd + j;
          const u64* r3 = g_rv64 + (size_t)(b0 + 3) * Wd + j;
          u64 u0 = ldrelax(r0), u1 = ldrelax(r1), u2 = ldrelax(r2), u3 = ldrelax(r3);
          waitquad(r0, r1, r2, r3, u0, u1, u2, u3, (unsigned)t);
          float4 rv;
          rv.x = tval(u0); rv.y = tval(u1); rv.z = tval(u2); rv.w = tval(u3);
          ((float4*)(sm + P1_V))[576 + j] = rv;  // same-wave write->read
        }
        float4 a0 = {0.f, 0.f, 0.f, 0.f}, a1 = {0.f, 0.f, 0.f, 0.f};
        float4 a2 = {0.f, 0.f, 0.f, 0.f}, a3 = {0.f, 0.f, 0.f, 0.f};
#pragma unroll 4
        for (int r = 0; r < 40; ++r) {
          float4 w4 = wp[(size_t)r * 512];
          float4 vv = vp[r];
          a0.x += w4.x * vv.x; a0.y += w4.y * vv.x; a0.z += w4.z * vv.x; a0.w += w4.w * vv.x;
          a1.x += w4.x * vv.y; a1.y += w4.y * vv.y; a1.z += w4.z * vv.y; a1.w += w4.w * vv.y;
          a2.x += w4.x * vv.z; a2.y += w4.y * vv.z; a2.z += w4.z * vv.z; a2.w += w4.w * vv.z;
          a3.x += w4.x * vv.w; a3.y += w4.y * vv.w; a3.z += w4.z * vv.w; a3.w += w4.w * vv.w;
        }
        float4* pacc = (float4*)(sm + P1_PACC);
        pacc[(ks * 4 + 0) * 33 + fg] = a0;
        pacc[(ks * 4 + 1) * 33 + fg] = a1;
        pacc[(ks * 4 + 2) * 33 + fg] = a2;
        pacc[(ks * 4 + 3) * 33 + fg] = a3;
      }
      __syncthreads();
      if (tid < 128) {  // K-reduce (16 partials) + LSTM; h published tagged
        const int bl = tid >> 5, l = tid & 31;
        const float* pb = sm + P1_PACC + bl * 132 + l;
        float gv0 = 0.f, gv1 = 0.f, gv2 = 0.f, gv3 = 0.f;
#pragma unroll
        for (int ks = 0; ks < 16; ++ks) {
          const float* pk = pb + ks * 528;
          gv0 += pk[0];
          gv1 += pk[32];
          gv2 += pk[64];
          gv3 += pk[96];
        }
        float ig = gv0 + sm[P1_BS + l];
        float fg = gv1 + sm[P1_BS + 32 + l];
        float gg = gv2 + sm[P1_BS + 64 + l];
        float og = gv3 + sm[P1_BS + 96 + l];
        float co = sm[P1_CC + tid];
        float cn = sigf(fg) * co + sigf(ig) * tanhf(gg);
        float hn = sigf(og) * tanhf(cn);
        sm[P1_CC + tid] = cn;
        sm[P1_HSL + tid] = hn;
        tstore(g_h64 + (size_t)(t & 1) * (Bb * Hh) + (size_t)(b0 + bl) * Hh + jb * 32 + l,
               (unsigned)(t + 1), hn);
      }
      __syncthreads();
      if (tid < 2 * IFs) {  // itf partials (32-col dot), 2 batches per thread
        const int o = tid >> 1, blh = tid & 1;
        const float4* wr = (const float4*)(sm + P1_WIF + o * 36);
        const float4* hA = (const float4*)(sm + P1_HSL) + (blh * 2 + 0) * 8;
        const float4* hB = (const float4*)(sm + P1_HSL) + (blh * 2 + 1) * 8;
        float accA = 0.f, accB = 0.f;
#pragma unroll
        for (int c4 = 0; c4 < 8; ++c4) {
          float4 w = wr[c4];
          float4 ha = hA[c4];
          float4 hb = hB[c4];
          accA += w.x * ha.x + w.y * ha.y + w.z * ha.z + w.w * ha.w;
          accB += w.x * hb.x + w.y * hb.y + w.z * hb.z + w.w * hb.w;
        }
        tstore(g_if64 + ((size_t)(b0 + blh * 2 + 0) * 16 + jb) * 200 + o,
               (unsigned)(t + 1), accA);
        tstore(g_if64 + ((size_t)(b0 + blh * 2 + 1) * 16 + jb) * 200 + o,
               (unsigned)(t + 1), accB);
      }
    }
  } else {
    // ======================= P2: DNC memory for batch b — R19 verbatim except
    // phase-1 gathers 16 jb partials (8 per thread, one combined poll).
    const int b = wg - NP1;
    float* SCR = sm + P2_SCR;
    float regL[32], regLT[32];
#pragma unroll
    for (int k = 0; k < 32; ++k) { regL[k] = 0.f; regLT[k] = 0.f; }
    for (int i = tid; i < Nn * 65; i += NT) sm[P2_MEM + i] = 0.f;
    if (tid < 128) { sm[P2_USAGE + tid] = 0.f; sm[P2_PREC + tid] = 0.f; sm[P2_RW + tid] = 0.f; }
    if (tid < IFs) sm[P2_BIF + tid] = b_if[tid];
    __syncthreads();
    // prologue: alloc for t=0 from usage=0
    if (tid < 64) {
      const int li = tid, i0 = 2 * li, i1 = i0 + 1;
      float u0 = sm[P2_USAGE + i0], u1 = sm[P2_USAGE + i1];
      int r0 = 0, r1 = 0;
      for (int jc = 0; jc < 32; ++jc) {
        float4 uj4 = *(const float4*)(sm + P2_USAGE + jc * 4);
#pragma unroll
        for (int e = 0; e < 4; ++e) {
          float uj = (&uj4.x)[e];
          int j = jc * 4 + e;
          r0 += (uj < u0 || (uj == u0 && j < i0)) ? 1 : 0;
          r1 += (uj < u1 || (uj == u1 && j < i1)) ? 1 : 0;
        }
      }
      sm[P2_SS + r0] = u0;
      sm[P2_SS + r1] = u1;
      float s0 = sm[P2_SS + i0], s1 = sm[P2_SS + i1];
      float p = s0 * s1;
#pragma unroll
      for (int off = 1; off < 64; off <<= 1) {
        float v = __shfl_up(p, off, 64);
        if (li >= off) p *= v;
      }
      float E = __shfl_up(p, 1, 64);
      if (li == 0) E = 1.f;
      sm[P2_SCAN + i0] = E * s0;
      sm[P2_SCAN + i1] = E * s0 * s1;
      float ex0 = (r0 > 0) ? sm[P2_SCAN + r0 - 1] : 1.f;
      float ex1 = (r1 > 0) ? sm[P2_SCAN + r1 - 1] : 1.f;
      sm[P2_ALLOC + i0] = (1.f - u0) * ex0;
      sm[P2_ALLOC + i1] = (1.f - u1) * ex1;
    }
    __syncthreads();

    for (int t = 0; t < Tt; ++t) {
      // ---- phase 1: tagged itf gather — 8 slots/thread, combined poll
      if (tid < 2 * IFs) {
        const int o = tid >> 1, hf = tid & 1;
        const u64* base = g_if64 + ((size_t)b * 16 + hf * 8) * 200 + o;
        const u64 *q0 = base, *q1 = base + 200, *q2 = base + 400, *q3 = base + 600;
        const u64 *q4 = base + 800, *q5 = base + 1000, *q6 = base + 1200, *q7 = base + 1400;
        u64 w0 = ldrelax(q0), w1 = ldrelax(q1), w2 = ldrelax(q2), w3 = ldrelax(q3);
        u64 w4 = ldrelax(q4), w5 = ldrelax(q5), w6 = ldrelax(q6), w7 = ldrelax(q7);
        const unsigned tg = (unsigned)(t + 1);
        while (((unsigned)(w0 >> 32)) != tg || ((unsigned)(w1 >> 32)) != tg ||
               ((unsigned)(w2 >> 32)) != tg || ((unsigned)(w3 >> 32)) != tg ||
               ((unsigned)(w4 >> 32)) != tg || ((unsigned)(w5 >> 32)) != tg ||
               ((unsigned)(w6 >> 32)) != tg || ((unsigned)(w7 >> 32)) != tg) {
          __builtin_amdgcn_s_sleep(1);
          w0 = ldrelax(q0); w1 = ldrelax(q1); w2 = ldrelax(q2); w3 = ldrelax(q3);
          w4 = ldrelax(q4); w5 = ldrelax(q5); w6 = ldrelax(q6); w7 = ldrelax(q7);
        }
        float s = tval(w0) + tval(w1) + tval(w2) + tval(w3)
                + tval(w4) + tval(w5) + tval(w6) + tval(w7);
        s += __shfl_xor(s, 1, 64);
        if (hf == 0) sm[P2_ITF + o] = s + sm[P2_BIF + o];
      }
      __syncthreads();
      // ---- phase 2: wave0 short block (scalars + ww from ALLOC + usage + wwsum)
      float kn_r = 0.f, rstr_r = 0.f, rm0_r = 0.f, rm1_r = 0.f, rm2_r = 0.f;
      if (tid < 64) {
        const int li = tid, i0 = 2 * li, i1 = i0 + 1;
        float wgag = sigf(sm[P2_ITF + 128]) * sigf(sm[P2_ITF + 129]);
        float rs = sm[P2_ITF + 194];
        rstr_r = (rs > 20.f) ? rs : log1pf(expf(rs));
        float m0 = sm[P2_ITF + 195], m1 = sm[P2_ITF + 196], m2 = sm[P2_ITF + 197];
        float mx = fmaxf(m0, fmaxf(m1, m2));
        float e0 = expf(m0 - mx), e1 = expf(m1 - mx), e2 = expf(m2 - mx);
        float es = e0 + e1 + e2;
        rm0_r = e0 / es; rm1_r = e1 / es; rm2_r = e2 / es;
        float rk = sm[P2_ITF + li];
        sm[P2_ERASE + li] = sigf(rk);
        sm[P2_WVEC + li] = sm[P2_ITF + 64 + li];
        float sq = rk * rk;
#pragma unroll
        for (int off = 32; off > 0; off >>= 1) sq += __shfl_xor(sq, off, 64);
        kn_r = sqrtf(sq) + 1e-8f;
        float u0 = sm[P2_USAGE + i0], u1 = sm[P2_USAGE + i1];
        float w0 = wgag * sm[P2_ALLOC + i0];
        float w1 = wgag * sm[P2_ALLOC + i1];
        sm[P2_WW + i0] = w0; sm[P2_WW + i1] = w1;
        sm[P2_USAGE + i0] = u0 + (1.f - u0) * w0;
        sm[P2_USAGE + i1] = u1 + (1.f - u1) * w1;
        float wws = w0 + w1;
#pragma unroll
        for (int off = 32; off > 0; off >>= 1) wws += __shfl_xor(wws, off, 64);
        if (li == 0) sm[P2_SCAL + S_WWSUM] = wws;
      }
      __syncthreads();
      // ---- phase 3: pass1 (fused mem+dot+mn + register link + bw/fw partials)
      {
        const int n = tid & 127, ws = tid >> 7;
        float4 er[4], wv[4], kf[4];
#pragma unroll
        for (int r = 0; r < 4; ++r) {
          er[r] = *(const float4*)(sm + P2_ERASE + ws * 16 + r * 4);
          wv[r] = *(const float4*)(sm + P2_WVEC + ws * 16 + r * 4);
          kf[r] = *(const float4*)(sm + P2_ITF + ws * 16 + r * 4);
        }
        float wwn = sm[P2_WW + n];
        float dotp = 0.f, mnp = 0.f;
        const int base = P2_MEM + n * 65 + ws * 16;
#pragma unroll
        for (int q = 0; q < 16; ++q) {
          float m = sm[base + q];
          float ee = (&er[q >> 2].x)[q & 3];
          float vv = (&wv[q >> 2].x)[q & 3];
          float kk = (&kf[q >> 2].x)[q & 3];
          m = m * (1.f - wwn * ee) + wwn * vv;
          sm[base + q] = m;
          dotp += kk * m;
          mnp += m * m;
        }
        SCR[ws * 128 + n] = dotp;
        SCR[512 + ws * 128 + n] = mnp;
        const int m = n, ns = ws;
        float wwm = wwn;
        float prn = sm[P2_PREC + m];
        float bwp = 0.f, fwp = 0.f;
#pragma unroll
        for (int kq = 0; kq < 8; ++kq) {
          float4 ww4 = *(const float4*)(sm + P2_WW + ns * 32 + kq * 4);
          float4 pr4 = *(const float4*)(sm + P2_PREC + ns * 32 + kq * 4);
          float4 rw4 = *(const float4*)(sm + P2_RW + ns * 32 + kq * 4);
#pragma unroll
          for (int e = 0; e < 4; ++e) {
            int k = kq * 4 + e;
            int nn = ns * 32 + k;
            float wwo = (&ww4.x)[e];
            float pro = (&pr4.x)[e];
            float rwo = (&rw4.x)[e];
            float L = regL[k];
            L = (1.f - wwo - wwm) * L + pro * wwm;
            if (nn == m) L = 0.f;
            regL[k] = L;
            bwp += L * rwo;
            float LT = regLT[k];
            LT = (1.f - wwm - wwo) * LT + prn * wwo;
            if (nn == m) LT = 0.f;
            regLT[k] = LT;
            fwp += LT * rwo;
          }
        }
        SCR[1024 + ns * 128 + m] = bwp;
        SCR[1536 + ns * 128 + m] = fwp;
      }
      __syncthreads();
      // ---- phase 4: softmax + combine + normalize (pass2 FUSED: read partials)
      if (tid < 64) {
        int i0 = 2 * tid, i1 = i0 + 1;
        float d0 = SCR[i0] + SCR[128 + i0] + SCR[256 + i0] + SCR[384 + i0];
        float d1 = SCR[i1] + SCR[128 + i1] + SCR[256 + i1] + SCR[384 + i1];
        float mn0 = sqrtf(SCR[512 + i0] + SCR[640 + i0] + SCR[768 + i0] + SCR[896 + i0]) + 1e-8f;
        float mn1 = sqrtf(SCR[512 + i1] + SCR[640 + i1] + SCR[768 + i1] + SCR[896 + i1]) + 1e-8f;
        float bw0 = SCR[1024 + i0] + SCR[1152 + i0] + SCR[1280 + i0] + SCR[1408 + i0];
        float bw1 = SCR[1024 + i1] + SCR[1152 + i1] + SCR[1280 + i1] + SCR[1408 + i1];
        float fw0 = SCR[1536 + i0] + SCR[1664 + i0] + SCR[1792 + i0] + SCR[1920 + i0];
        float fw1 = SCR[1536 + i1] + SCR[1664 + i1] + SCR[1792 + i1] + SCR[1920 + i1];
        float q0 = d0 / (kn_r * mn0) * rstr_r;
        float q1 = d1 / (kn_r * mn1) * rstr_r;
        float mx = fmaxf(q0, q1);
#pragma unroll
        for (int off = 32; off > 0; off >>= 1) mx = fmaxf(mx, __shfl_xor(mx, off, 64));
        float e0 = expf(q0 - mx), e1 = expf(q1 - mx);
        float es = e0 + e1;
#pragma unroll
        for (int off = 32; off > 0; off >>= 1) es += __shfl_xor(es, off, 64);
        float wv0 = rm0_r * bw0 + rm1_r * fw0 + rm2_r * (e0 / es) + 1e-8f;
        float wv1 = rm0_r * bw1 + rm1_r * fw1 + rm2_r * (e1 / es) + 1e-8f;
        float wsum = wv0 + wv1;
#pragma unroll
        for (int off = 32; off > 0; off >>= 1) wsum += __shfl_xor(wsum, off, 64);
        sm[P2_RW + i0] = wv0 / wsum;
        sm[P2_RW + i1] = wv1 / wsum;
      }
      __syncthreads();
      // ---- phase 5: rvec partials
      {
        const int w = tid & 63, ns8 = tid >> 6;
        float4 rw4[4];
#pragma unroll
        for (int r = 0; r < 4; ++r)
          rw4[r] = *(const float4*)(sm + P2_RW + ns8 * 16 + r * 4);
        float p = 0.f;
#pragma unroll
        for (int k = 0; k < 16; ++k)
          p += (&rw4[k >> 2].x)[k & 3] * sm[P2_MEM + (ns8 * 16 + k) * 65 + w];
        SCR[ns8 * 64 + w] = p;
      }
      __syncthreads();
      // ---- phase 6 (merged): rvec reduce+publish | h gather | alloc | prec
      if (tid < 64) {          // rvec reduce -> tagged store (critical-path exit)
        float r = 0.f;
#pragma unroll
        for (int s2 = 0; s2 < 8; ++s2) r += SCR[s2 * 64 + tid];
        sm[P2_H + 512 + tid] = r;
        tstore(g_rv64 + (size_t)b * Wd + tid, (unsigned)(t + 1), r);
      } else if (tid < 320) {  // tagged h gather — concurrent wait
        const int idx = tid - 64;
        const u64* hsrc = g_h64 + (size_t)(t & 1) * (Bb * Hh) + (size_t)b * Hh;
        const u64* a0 = hsrc + idx * 2;
        const u64* a1 = hsrc + idx * 2 + 1;
        u64 v0 = ldrelax(a0), v1 = ldrelax(a1);
        waitpair(a0, a1, v0, v1, (unsigned)(t + 1));
        sm[P2_H + idx * 2] = tval(v0);
        sm[P2_H + idx * 2 + 1] = tval(v1);
      } else if (tid < 384) {  // next step's alloc from usage(t) (wave 5)
        const int li = tid - 320, i0 = 2 * li, i1 = i0 + 1;
        float u0 = sm[P2_USAGE + i0], u1 = sm[P2_USAGE + i1];
        int r0 = 0, r1 = 0;
        for (int jc = 0; jc < 32; ++jc) {
          float4 uj4 = *(const float4*)(sm + P2_USAGE + jc * 4);
#pragma unroll
          for (int e = 0; e < 4; ++e) {
            float uj = (&uj4.x)[e];
            int j = jc * 4 + e;
            r0 += (uj < u0 || (uj == u0 && j < i0)) ? 1 : 0;
            r1 += (uj < u1 || (uj == u1 && j < i1)) ? 1 : 0;
          }
        }
        sm[P2_SS + r0] = u0;
        sm[P2_SS + r1] = u1;
        float s0 = sm[P2_SS + i0], s1 = sm[P2_SS + i1];
        float p = s0 * s1;
#pragma unroll
        for (int off = 1; off < 64; off <<= 1) {
          float v = __shfl_up(p, off, 64);
          if (li >= off) p *= v;
        }
        float E = __shfl_up(p, 1, 64);
        if (li == 0) E = 1.f;
        sm[P2_SCAN + i0] = E * s0;
        sm[P2_SCAN + i1] = E * s0 * s1;
        float ex0 = (r0 > 0) ? sm[P2_SCAN + r0 - 1] : 1.f;
        float ex1 = (r1 > 0) ? sm[P2_SCAN + r1 - 1] : 1.f;
        sm[P2_ALLOC + i0] = (1.f - u0) * ex0;
        sm[P2_ALLOC + i1] = (1.f - u1) * ex1;
      } else {                 // prec update (hoisted from old pass2)
        const int n = tid - 384;   // 0..127
        float wws = sm[P2_SCAL + S_WWSUM];
        sm[P2_PREC + n] = (1.f - wws) * sm[P2_PREC + n] + sm[P2_WW + n];
      }
      __syncthreads();
      // ---- phase 7: out projection (no trailing barrier needed)
      {
        const int o = tid >> 3, seg = tid & 7;
        const float4* wrow = (const float4*)(W_out + (size_t)o * 576) + seg * 18;
        const float4* hb = (const float4*)(sm + P2_H) + seg * 18;
        float p = 0.f;
#pragma unroll
        for (int q = 0; q < 18; ++q) {
          float4 w = wrow[q]; float4 h = hb[q];
          p += w.x * h.x + w.y * h.y + w.z * h.z + w.w * h.w;
        }
        p += __shfl_down(p, 4, 8);
        p += __shfl_down(p, 2, 8);
        p += __shfl_down(p, 1, 8);
        if (seg == 0) out[((size_t)b * Tt + t) * Oo + o] = p + b_out[o];
      }
    }
  }
}

extern "C" void kernel_launch(void* const* d_in, const int* in_sizes, int n_in,
                              void* d_out, int out_size, void* d_ws, size_t ws_size,
                              hipStream_t stream) {
  (void)in_sizes; (void)n_in; (void)d_ws; (void)ws_size; (void)out_size;
  const float* x    = (const float*)d_in[0];
  const float* W_ih = (const float*)d_in[1];
  const float* W_hh = (const float*)d_in[2];
  const float* b_ih = (const float*)d_in[3];
  const float* b_hh = (const float*)d_in[4];
  const float* W_if = (const float*)d_in[5];
  const float* b_if = (const float*)d_in[6];
  const float* W_out = (const float*)d_in[7];
  const float* b_out = (const float*)d_in[8];
  float* out = (float*)d_out;

  dnc_init<<<320, TIN, 0, stream>>>(W_ih, W_hh, b_ih, b_hh);

  hipFuncSetAttribute((const void*)dnc_main,
                      hipFuncAttributeMaxDynamicSharedMemorySize, SMEM_BYTES);

  void* args[] = {(void*)&x, (void*)&W_if, (void*)&b_if,
                  (void*)&W_out, (void*)&b_out, (void*)&out};
  hipLaunchCooperativeKernel((void*)dnc_main, dim3(NWG), dim3(NT), args,
                             SMEM_BYTES, stream);
}